// Round 1
// baseline (7893.104 us; speedup 1.0000x reference)
//
#include <hip/hip_runtime.h>
#include <hip/hip_bf16.h>
#include <hip/hip_fp16.h>

#define TT 2048
#define BB 16
#define DD 256
#define GG 1024   // 4U
#define UU 256
#define NRES 12   // R chunks kept register-resident per column

using f32x4  = __attribute__((ext_vector_type(4))) float;
using short8 = __attribute__((ext_vector_type(8))) short;
using h2_t   = __attribute__((ext_vector_type(2))) _Float16;

static __device__ __forceinline__ unsigned short f2h_u(float f){
  _Float16 h = (_Float16)f;
  return __builtin_bit_cast(unsigned short, h);
}
static __device__ __forceinline__ float h2f(unsigned short u){
  return (float)__builtin_bit_cast(_Float16, u);
}
static __device__ __forceinline__ unsigned short f2bf_u(float f){
  __hip_bfloat16 b = __float2bfloat16(f);
  return __builtin_bit_cast(unsigned short, b);
}
static __device__ __forceinline__ float fdot2u(unsigned int a, unsigned int b, float c){
#if __has_builtin(__builtin_amdgcn_fdot2)
  return __builtin_amdgcn_fdot2(__builtin_bit_cast(h2_t, a), __builtin_bit_cast(h2_t, b), c, false);
#else
  h2_t x = __builtin_bit_cast(h2_t, a);
  h2_t y = __builtin_bit_cast(h2_t, b);
  return c + (float)x[0]*(float)y[0] + (float)x[1]*(float)y[1];
#endif
}
static __device__ __forceinline__ float sigmoid_f(float x){
  return 1.0f / (1.0f + __expf(-x));
}
static __device__ __forceinline__ float tanh_f(float x){
  float ax = fabsf(x);
  float e  = __expf(2.0f*ax);          // overflow -> inf is fine: r -> 1
  float r  = 1.0f - 2.0f/(e + 1.0f);
  return copysignf(r, x);
}

// ---- converts -------------------------------------------------------------
__global__ __launch_bounds__(256) void cvt_x_kernel(const float* __restrict__ x,
                                                    unsigned short* __restrict__ xh){
  int gid = blockIdx.x*256 + threadIdx.x;          // 2,097,152 threads, 4 elems each
  const float4* xv = (const float4*)x;
  float4 v = xv[gid];
  unsigned int u0 = (unsigned int)f2bf_u(v.x) | ((unsigned int)f2bf_u(v.y) << 16);
  unsigned int u1 = (unsigned int)f2bf_u(v.z) | ((unsigned int)f2bf_u(v.w) << 16);
  ((uint2*)xh)[gid] = make_uint2(u0, u1);
}

// W [256][1024] f32 -> W^T bf16 [dir][1024][256]
__global__ __launch_bounds__(256) void cvt_wt_kernel(const float* __restrict__ Wf,
                                                     const float* __restrict__ Wb,
                                                     unsigned short* __restrict__ wt){
  int gid = blockIdx.x*256 + threadIdx.x;          // 2*1024*256 = 524288
  int d   = gid >> 18;
  int rem = gid & 262143;
  int n   = rem >> 8;
  int k   = rem & 255;
  const float* src = d ? Wb : Wf;
  wt[gid] = f2bf_u(src[k*GG + n]);
}

// R [256][1024] f32 -> f16 packed [dir][32][1024] uint4 (8 consecutive k per col)
__global__ __launch_bounds__(256) void cvt_r_kernel(const float* __restrict__ Rf,
                                                    const float* __restrict__ Rb,
                                                    uint4* __restrict__ r4){
  int gid = blockIdx.x*256 + threadIdx.x;          // 2*32*1024 = 65536
  int d   = gid >> 15;
  int rem = gid & 32767;
  int k8  = rem >> 10;
  int j   = rem & 1023;
  const float* src = d ? Rb : Rf;
  unsigned int u[4];
#pragma unroll
  for (int e2 = 0; e2 < 4; ++e2){
    unsigned short lo = f2h_u(src[(k8*8 + e2*2    )*GG + j]);
    unsigned short hi = f2h_u(src[(k8*8 + e2*2 + 1)*GG + j]);
    u[e2] = (unsigned int)lo | ((unsigned int)hi << 16);
  }
  r4[gid] = make_uint4(u[0], u[1], u[2], u[3]);
}

// ---- proj GEMM: C[row][n] = sum_k A[row][k] * WT[n][k], bf16 MFMA, f16 out --
__global__ __launch_bounds__(256) void gemm_proj(const unsigned short* __restrict__ Ah,
                                                 const unsigned short* __restrict__ BTh,
                                                 unsigned short* __restrict__ Cd,
                                                 int tstart, int Tc){
  __shared__ __align__(16) unsigned short smem[18432];  // 36864 B
  unsigned short* sA = smem;             // [128][72]
  unsigned short* sB = smem + 9216;      // [128][72]
  unsigned short* sC = smem;             // [128][136] (reuses sA/sB)

  int bt  = blockIdx.x;
  int nt  = bt & 7;
  int rem = bt >> 3;
  int mtpb = Tc >> 7;
  int mt  = rem % mtpb;
  int bb  = rem / mtpb;
  int tid = threadIdx.x;

  const unsigned short* Ab = Ah  + ((size_t)(bb*TT + tstart + mt*128))*DD;
  const unsigned short* Bb = BTh + (size_t)nt*128*DD;

  int w = tid >> 6, lane = tid & 63, l15 = lane & 15, l4 = lane >> 4;
  int wm = w >> 1, wn = w & 1;

  f32x4 zero4 = {0.0f, 0.0f, 0.0f, 0.0f};
  f32x4 acc[4][4];
#pragma unroll
  for (int i = 0; i < 4; ++i)
#pragma unroll
    for (int j = 0; j < 4; ++j) acc[i][j] = zero4;

  for (int kt = 0; kt < 4; ++kt){
    __syncthreads();
#pragma unroll
    for (int i = 0; i < 4; ++i){
      int ch = tid + i*256;
      int r = ch >> 3, c8 = ch & 7;
      *(uint4*)(sA + r*72 + c8*8) = *(const uint4*)(Ab + (size_t)r*DD + kt*64 + c8*8);
      *(uint4*)(sB + r*72 + c8*8) = *(const uint4*)(Bb + (size_t)r*DD + kt*64 + c8*8);
    }
    __syncthreads();
#pragma unroll
    for (int ks = 0; ks < 2; ++ks){
      short8 a[4], b[4];
#pragma unroll
      for (int mf = 0; mf < 4; ++mf)
        a[mf] = *(const short8*)(sA + (wm*64 + mf*16 + l15)*72 + ks*32 + l4*8);
#pragma unroll
      for (int nf = 0; nf < 4; ++nf)
        b[nf] = *(const short8*)(sB + (wn*64 + nf*16 + l15)*72 + ks*32 + l4*8);
#pragma unroll
      for (int mf = 0; mf < 4; ++mf)
#pragma unroll
        for (int nf = 0; nf < 4; ++nf)
          acc[mf][nf] = __builtin_amdgcn_mfma_f32_16x16x32_bf16(a[mf], b[nf], acc[mf][nf], 0, 0, 0);
    }
  }
  __syncthreads();
#pragma unroll
  for (int mf = 0; mf < 4; ++mf)
#pragma unroll
    for (int nf = 0; nf < 4; ++nf)
#pragma unroll
      for (int r = 0; r < 4; ++r)
        sC[(wm*64 + mf*16 + l4*4 + r)*136 + wn*64 + nf*16 + l15] = f2h_u(acc[mf][nf][r]);
  __syncthreads();
  unsigned short* Cb = Cd + ((size_t)bb*Tc + mt*128)*GG + nt*128;
#pragma unroll
  for (int i = 0; i < 8; ++i){
    int ch = tid + i*256;
    int r = ch >> 4, c = ch & 15;
    *(uint4*)(Cb + (size_t)r*GG + c*8) = *(const uint4*)(sC + r*136 + c*8);
  }
}

// ---- persistent per-(batch,dir) LSTM scan ---------------------------------
__global__ __launch_bounds__(512, 2) void lstm_scan(
    const unsigned short* __restrict__ proj,   // [2][16][Tc][1024] f16
    const uint4* __restrict__ R4,              // [2][32][1024] packed f16
    const float* __restrict__ bcf,
    const float* __restrict__ bcb,
    float* __restrict__ out,                   // [16][2048][512] f32
    float* __restrict__ stH, float* __restrict__ stC,
    int t0, int t1, int Tc, int first)
{
  int blk = blockIdx.x;
  int b = blk & 15, d = blk >> 4;
  int tid = threadIdx.x;

  __shared__ __align__(16) unsigned short h16[256];
  __shared__ float g_lds[1024];

  const uint4* Rd = R4 + (size_t)d*32768;
  const unsigned short* pb = proj + ((size_t)(d*16 + b))*Tc*GG;
  const float* bc = d ? bcb : bcf;
  int sidx = (d*16 + b)*256 + tid;

  float c_reg = 0.0f, h_last = 0.0f;
  if (tid < 256){
    float h0 = 0.0f;
    if (!first){ c_reg = stC[sidx]; h0 = stH[sidx]; }
    h16[tid] = f2h_u(h0);
    h_last = h0;
  }

  uint4 ra[NRES], rb[NRES];
#pragma unroll
  for (int i = 0; i < NRES; ++i){
    ra[i] = Rd[i*GG + tid];
    rb[i] = Rd[i*GG + tid + 512];
  }

  const uint4* hl = (const uint4*)h16;
  int lr    = d ? (t1 - 1 - t0) : 0;
  int lstep = d ? -1 : 1;
  const unsigned short* prow = pb + (size_t)lr*GG;
  unsigned short pc0 = prow[tid];
  unsigned short pc1 = prow[tid + 512];
  __syncthreads();

  for (int t = t0; t < t1; ++t){
    prow += lstep*GG;
    unsigned short pn0 = 0, pn1 = 0;
    if (t + 1 < t1){ pn0 = prow[tid]; pn1 = prow[tid + 512]; }

    uint4 pfa[4], pfb[4];
#pragma unroll
    for (int i = 0; i < 4; ++i){
      pfa[i] = Rd[(NRES + i)*GG + tid];
      pfb[i] = Rd[(NRES + i)*GG + tid + 512];
    }

    float a0=0,a1=0,a2=0,a3=0, b0=0,b1=0,b2=0,b3=0;
#pragma unroll
    for (int i = 0; i < NRES; ++i){
      uint4 h8 = hl[i];
      a0 = fdot2u(ra[i].x, h8.x, a0);
      a1 = fdot2u(ra[i].y, h8.y, a1);
      a2 = fdot2u(ra[i].z, h8.z, a2);
      a3 = fdot2u(ra[i].w, h8.w, a3);
      b0 = fdot2u(rb[i].x, h8.x, b0);
      b1 = fdot2u(rb[i].y, h8.y, b1);
      b2 = fdot2u(rb[i].z, h8.z, b2);
      b3 = fdot2u(rb[i].w, h8.w, b3);
    }
#pragma unroll
    for (int i = NRES; i < 32; ++i){
      uint4 h8 = hl[i];
      uint4 va = pfa[(i - NRES) & 3];
      uint4 vb = pfb[(i - NRES) & 3];
      if (i + 4 < 32){
        pfa[(i - NRES) & 3] = Rd[(i + 4)*GG + tid];
        pfb[(i - NRES) & 3] = Rd[(i + 4)*GG + tid + 512];
      }
      a0 = fdot2u(va.x, h8.x, a0); a1 = fdot2u(va.y, h8.y, a1);
      a2 = fdot2u(va.z, h8.z, a2); a3 = fdot2u(va.w, h8.w, a3);
      b0 = fdot2u(vb.x, h8.x, b0); b1 = fdot2u(vb.y, h8.y, b1);
      b2 = fdot2u(vb.z, h8.z, b2); b3 = fdot2u(vb.w, h8.w, b3);
    }

    g_lds[tid]       = h2f(pc0) + ((a0 + a1) + (a2 + a3));
    g_lds[tid + 512] = h2f(pc1) + ((b0 + b1) + (b2 + b3));
    __syncthreads();

    if (tid < 256){
      float gi = g_lds[tid];
      float gf = g_lds[tid + 256];
      float go = g_lds[tid + 512];
      float gc = g_lds[tid + 768];
      float ig = sigmoid_f(gi);
      float fg = sigmoid_f(gf);
      float og = sigmoid_f(go);
      float cand = tanh_f(gc + bc[tid]);
      c_reg = sigmoid_f(fg*c_reg + ig*cand);        // faithful quirk
      float h = tanh_f(c_reg) * og;                 // faithful quirk
      out[((size_t)b*TT + t)*512 + d*256 + tid] = h;
      h16[tid] = f2h_u(h);
      h_last = h;
    }
    pc0 = pn0; pc1 = pn1;
    __syncthreads();
  }

  if (tid < 256){
    stH[sidx] = h_last;
    stC[sidx] = c_reg;
  }
}

// ---- launcher -------------------------------------------------------------
extern "C" void kernel_launch(void* const* d_in, const int* in_sizes, int n_in,
                              void* d_out, int out_size, void* d_ws, size_t ws_size,
                              hipStream_t stream){
  const float* x   = (const float*)d_in[0];
  const float* Wf  = (const float*)d_in[1];
  const float* Rf  = (const float*)d_in[2];
  const float* bcf = (const float*)d_in[3];
  const float* Wb  = (const float*)d_in[4];
  const float* Rb  = (const float*)d_in[5];
  const float* bcb = (const float*)d_in[6];
  float* out = (float*)d_out;
  char* ws = (char*)d_ws;

  const size_t OFF_XH   = 0;                      // 16 MiB: x bf16
  const size_t OFF_WT   = 16777216;               // 1 MiB: W^T bf16 both dirs
  const size_t OFF_R4   = OFF_WT + 1048576;       // 1 MiB: R f16 packed
  const size_t OFF_STH  = OFF_R4 + 1048576;       // 32 KiB h state
  const size_t OFF_STC  = OFF_STH + 32768;        // 32 KiB c state
  const size_t OFF_PROJ = OFF_STC + 32768;        // proj chunk buffer

  unsigned short* xh   = (unsigned short*)(ws + OFF_XH);
  unsigned short* wt   = (unsigned short*)(ws + OFF_WT);
  uint4*          r4   = (uint4*)(ws + OFF_R4);
  float*          stH  = (float*)(ws + OFF_STH);
  float*          stC  = (float*)(ws + OFF_STC);
  unsigned short* proj = (unsigned short*)(ws + OFF_PROJ);

  int Tc = TT;  // time-chunk; shrink if ws too small (proj = 65536*Tc bytes)
  while (Tc > 128 && OFF_PROJ + (size_t)65536*Tc > ws_size) Tc >>= 1;

  cvt_x_kernel<<<8192, 256, 0, stream>>>(x, xh);
  cvt_wt_kernel<<<2048, 256, 0, stream>>>(Wf, Wb, wt);
  cvt_r_kernel<<<256, 256, 0, stream>>>(Rf, Rb, r4);

  int nch = TT / Tc;
  for (int ch = 0; ch < nch; ++ch){
    int t0 = ch*Tc, t1 = t0 + Tc;
    int grid = 8*(Tc >> 7)*16;
    gemm_proj<<<grid, 256, 0, stream>>>(xh, wt,          proj,                        t0,      Tc);
    gemm_proj<<<grid, 256, 0, stream>>>(xh, wt + 262144, proj + (size_t)16*Tc*GG,     TT - t1, Tc);
    lstm_scan<<<32, 512, 0, stream>>>(proj, r4, bcf, bcb, out, stH, stC, t0, t1, Tc, ch == 0 ? 1 : 0);
  }
}

// Round 2
// 4555.693 us; speedup vs baseline: 1.7326x; 1.7326x over previous
//
#include <hip/hip_runtime.h>
#include <hip/hip_bf16.h>
#include <hip/hip_fp16.h>

#define TT 2048
#define BB 16
#define DD 256
#define GG 1024   // 4U
#define UU 256
#define NLDS 7    // R chunks 0..6 in LDS (112 KB)
#define NRES 25   // R chunks 7..31 register-resident (200 VGPRs)

using f32x4  = __attribute__((ext_vector_type(4))) float;
using short8 = __attribute__((ext_vector_type(8))) short;
using h2_t   = __attribute__((ext_vector_type(2))) _Float16;

static __device__ __forceinline__ unsigned short f2h_u(float f){
  _Float16 h = (_Float16)f;
  return __builtin_bit_cast(unsigned short, h);
}
static __device__ __forceinline__ float h2f(unsigned short u){
  return (float)__builtin_bit_cast(_Float16, u);
}
static __device__ __forceinline__ unsigned short f2bf_u(float f){
  __hip_bfloat16 b = __float2bfloat16(f);
  return __builtin_bit_cast(unsigned short, b);
}
static __device__ __forceinline__ float fdot2u(unsigned int a, unsigned int b, float c){
#if __has_builtin(__builtin_amdgcn_fdot2)
  return __builtin_amdgcn_fdot2(__builtin_bit_cast(h2_t, a), __builtin_bit_cast(h2_t, b), c, false);
#else
  h2_t x = __builtin_bit_cast(h2_t, a);
  h2_t y = __builtin_bit_cast(h2_t, b);
  return c + (float)x[0]*(float)y[0] + (float)x[1]*(float)y[1];
#endif
}
static __device__ __forceinline__ float sigmoid_f(float x){
  return 1.0f / (1.0f + __expf(-x));
}
static __device__ __forceinline__ float tanh_f(float x){
  float ax = fabsf(x);
  float e  = __expf(2.0f*ax);          // overflow -> inf is fine: r -> 1
  float r  = 1.0f - 2.0f/(e + 1.0f);
  return copysignf(r, x);
}

// ---- converts -------------------------------------------------------------
__global__ __launch_bounds__(256) void cvt_x_kernel(const float* __restrict__ x,
                                                    unsigned short* __restrict__ xh){
  int gid = blockIdx.x*256 + threadIdx.x;          // 2,097,152 threads, 4 elems each
  const float4* xv = (const float4*)x;
  float4 v = xv[gid];
  unsigned int u0 = (unsigned int)f2bf_u(v.x) | ((unsigned int)f2bf_u(v.y) << 16);
  unsigned int u1 = (unsigned int)f2bf_u(v.z) | ((unsigned int)f2bf_u(v.w) << 16);
  ((uint2*)xh)[gid] = make_uint2(u0, u1);
}

// W [256][1024] f32 -> W^T bf16 [dir][1024][256]
__global__ __launch_bounds__(256) void cvt_wt_kernel(const float* __restrict__ Wf,
                                                     const float* __restrict__ Wb,
                                                     unsigned short* __restrict__ wt){
  int gid = blockIdx.x*256 + threadIdx.x;          // 2*1024*256 = 524288
  int d   = gid >> 18;
  int rem = gid & 262143;
  int n   = rem >> 8;
  int k   = rem & 255;
  const float* src = d ? Wb : Wf;
  wt[gid] = f2bf_u(src[k*GG + n]);
}

// R [256][1024] f32 -> f16 packed [dir][32][1024] uint4 (8 consecutive k per col)
__global__ __launch_bounds__(256) void cvt_r_kernel(const float* __restrict__ Rf,
                                                    const float* __restrict__ Rb,
                                                    uint4* __restrict__ r4){
  int gid = blockIdx.x*256 + threadIdx.x;          // 2*32*1024 = 65536
  int d   = gid >> 15;
  int rem = gid & 32767;
  int k8  = rem >> 10;
  int j   = rem & 1023;
  const float* src = d ? Rb : Rf;
  unsigned int u[4];
#pragma unroll
  for (int e2 = 0; e2 < 4; ++e2){
    unsigned short lo = f2h_u(src[(k8*8 + e2*2    )*GG + j]);
    unsigned short hi = f2h_u(src[(k8*8 + e2*2 + 1)*GG + j]);
    u[e2] = (unsigned int)lo | ((unsigned int)hi << 16);
  }
  r4[gid] = make_uint4(u[0], u[1], u[2], u[3]);
}

// ---- proj GEMM: C[row][n] = sum_k A[row][k] * WT[n][k], bf16 MFMA, f16 out --
__global__ __launch_bounds__(256) void gemm_proj(const unsigned short* __restrict__ Ah,
                                                 const unsigned short* __restrict__ BTh,
                                                 unsigned short* __restrict__ Cd,
                                                 int tstart, int Tc){
  __shared__ __align__(16) unsigned short smem[18432];  // 36864 B
  unsigned short* sA = smem;             // [128][72]
  unsigned short* sB = smem + 9216;      // [128][72]
  unsigned short* sC = smem;             // [128][136] (reuses sA/sB)

  int bt  = blockIdx.x;
  int nt  = bt & 7;
  int rem = bt >> 3;
  int mtpb = Tc >> 7;
  int mt  = rem % mtpb;
  int bb  = rem / mtpb;
  int tid = threadIdx.x;

  const unsigned short* Ab = Ah  + ((size_t)(bb*TT + tstart + mt*128))*DD;
  const unsigned short* Bb = BTh + (size_t)nt*128*DD;

  int w = tid >> 6, lane = tid & 63, l15 = lane & 15, l4 = lane >> 4;
  int wm = w >> 1, wn = w & 1;

  f32x4 zero4 = {0.0f, 0.0f, 0.0f, 0.0f};
  f32x4 acc[4][4];
#pragma unroll
  for (int i = 0; i < 4; ++i)
#pragma unroll
    for (int j = 0; j < 4; ++j) acc[i][j] = zero4;

  for (int kt = 0; kt < 4; ++kt){
    __syncthreads();
#pragma unroll
    for (int i = 0; i < 4; ++i){
      int ch = tid + i*256;
      int r = ch >> 3, c8 = ch & 7;
      *(uint4*)(sA + r*72 + c8*8) = *(const uint4*)(Ab + (size_t)r*DD + kt*64 + c8*8);
      *(uint4*)(sB + r*72 + c8*8) = *(const uint4*)(Bb + (size_t)r*DD + kt*64 + c8*8);
    }
    __syncthreads();
#pragma unroll
    for (int ks = 0; ks < 2; ++ks){
      short8 a[4], b[4];
#pragma unroll
      for (int mf = 0; mf < 4; ++mf)
        a[mf] = *(const short8*)(sA + (wm*64 + mf*16 + l15)*72 + ks*32 + l4*8);
#pragma unroll
      for (int nf = 0; nf < 4; ++nf)
        b[nf] = *(const short8*)(sB + (wn*64 + nf*16 + l15)*72 + ks*32 + l4*8);
#pragma unroll
      for (int mf = 0; mf < 4; ++mf)
#pragma unroll
        for (int nf = 0; nf < 4; ++nf)
          acc[mf][nf] = __builtin_amdgcn_mfma_f32_16x16x32_bf16(a[mf], b[nf], acc[mf][nf], 0, 0, 0);
    }
  }
  __syncthreads();
#pragma unroll
  for (int mf = 0; mf < 4; ++mf)
#pragma unroll
    for (int nf = 0; nf < 4; ++nf)
#pragma unroll
      for (int r = 0; r < 4; ++r)
        sC[(wm*64 + mf*16 + l4*4 + r)*136 + wn*64 + nf*16 + l15] = f2h_u(acc[mf][nf][r]);
  __syncthreads();
  unsigned short* Cb = Cd + ((size_t)bb*Tc + mt*128)*GG + nt*128;
#pragma unroll
  for (int i = 0; i < 8; ++i){
    int ch = tid + i*256;
    int r = ch >> 4, c = ch & 15;
    *(uint4*)(Cb + (size_t)r*GG + c*8) = *(const uint4*)(sC + r*136 + c*8);
  }
}

// ---- persistent per-(batch,dir) LSTM scan, R fully CU-resident ------------
// R chunks 0..NLDS-1 live in LDS; chunks NLDS..31 live in registers.
// Zero per-step global traffic for R.
__global__ __launch_bounds__(512, 2) void lstm_scan(
    const unsigned short* __restrict__ proj,   // [2][16][Tc][1024] f16
    const uint4* __restrict__ R4,              // [2][32][1024] packed f16
    const float* __restrict__ bcf,
    const float* __restrict__ bcb,
    float* __restrict__ out,                   // [16][2048][512] f32
    float* __restrict__ stH, float* __restrict__ stC,
    int t0, int t1, int Tc, int first)
{
  int blk = blockIdx.x;
  int b = blk & 15, d = blk >> 4;
  int tid = threadIdx.x;

  __shared__ __align__(16) uint4 rlds[NLDS*1024];      // 112 KB
  __shared__ __align__(16) unsigned short h16[256];    // 512 B
  __shared__ float g_lds[1024];                        // 4 KB

  const uint4* Rd = R4 + (size_t)d*32768;
  const unsigned short* pb = proj + ((size_t)(d*16 + b))*Tc*GG;
  const float* bc = d ? bcb : bcf;
  int sidx = (d*16 + b)*256 + tid;

  // stage LDS-resident R chunks (each thread fills the two columns it reads)
#pragma unroll
  for (int i = 0; i < NLDS; ++i){
    rlds[i*1024 + tid]       = Rd[i*GG + tid];
    rlds[i*1024 + tid + 512] = Rd[i*GG + tid + 512];
  }
  // register-resident R chunks
  uint4 ra[NRES], rb[NRES];
#pragma unroll
  for (int i = 0; i < NRES; ++i){
    ra[i] = Rd[(NLDS + i)*GG + tid];
    rb[i] = Rd[(NLDS + i)*GG + tid + 512];
  }

  float c_reg = 0.0f, h_last = 0.0f, bc_r = 0.0f;
  float* out_base = nullptr;
  if (tid < 256){
    float h0 = 0.0f;
    if (!first){ c_reg = stC[sidx]; h0 = stH[sidx]; }
    h16[tid] = f2h_u(h0);
    h_last = h0;
    bc_r = bc[tid];
    out_base = out + (size_t)b*TT*512 + d*256 + tid;
  }

  const uint4* hl = (const uint4*)h16;
  int lr    = d ? (t1 - 1 - t0) : 0;
  int lstep = d ? -1 : 1;
  const unsigned short* prow = pb + (size_t)lr*GG;
  unsigned short pc0 = prow[tid];
  unsigned short pc1 = prow[tid + 512];
  __syncthreads();

  for (int t = t0; t < t1; ++t){
    prow += lstep*GG;
    unsigned short pn0 = 0, pn1 = 0;
    if (t + 1 < t1){ pn0 = prow[tid]; pn1 = prow[tid + 512]; }

    // fold proj into accumulator init
    float a0 = h2f(pc0), a1 = 0.f, a2 = 0.f, a3 = 0.f;
    float b0 = h2f(pc1), b1 = 0.f, b2 = 0.f, b3 = 0.f;

    // LDS-resident chunks (contiguous b128 reads, conflict-free)
#pragma unroll
    for (int i = 0; i < NLDS; ++i){
      uint4 h8 = hl[i];
      uint4 va = rlds[i*1024 + tid];
      uint4 vb = rlds[i*1024 + tid + 512];
      a0 = fdot2u(va.x, h8.x, a0); a1 = fdot2u(va.y, h8.y, a1);
      a2 = fdot2u(va.z, h8.z, a2); a3 = fdot2u(va.w, h8.w, a3);
      b0 = fdot2u(vb.x, h8.x, b0); b1 = fdot2u(vb.y, h8.y, b1);
      b2 = fdot2u(vb.z, h8.z, b2); b3 = fdot2u(vb.w, h8.w, b3);
    }
    // register-resident chunks (pure VALU)
#pragma unroll
    for (int i = 0; i < NRES; ++i){
      uint4 h8 = hl[NLDS + i];
      a0 = fdot2u(ra[i].x, h8.x, a0); a1 = fdot2u(ra[i].y, h8.y, a1);
      a2 = fdot2u(ra[i].z, h8.z, a2); a3 = fdot2u(ra[i].w, h8.w, a3);
      b0 = fdot2u(rb[i].x, h8.x, b0); b1 = fdot2u(rb[i].y, h8.y, b1);
      b2 = fdot2u(rb[i].z, h8.z, b2); b3 = fdot2u(rb[i].w, h8.w, b3);
    }

    g_lds[tid]       = (a0 + a1) + (a2 + a3);
    g_lds[tid + 512] = (b0 + b1) + (b2 + b3);
    __syncthreads();

    if (tid < 256){
      float gi = g_lds[tid];
      float gf = g_lds[tid + 256];
      float go = g_lds[tid + 512];
      float gc = g_lds[tid + 768];
      float ig = sigmoid_f(gi);
      float fg = sigmoid_f(gf);
      float og = sigmoid_f(go);
      float cand = tanh_f(gc + bc_r);
      c_reg = sigmoid_f(fg*c_reg + ig*cand);        // faithful quirk
      float h = tanh_f(c_reg) * og;                 // faithful quirk
      out_base[(size_t)t*512] = h;
      h16[tid] = f2h_u(h);
      h_last = h;
    }
    pc0 = pn0; pc1 = pn1;
    __syncthreads();
  }

  if (tid < 256){
    stH[sidx] = h_last;
    stC[sidx] = c_reg;
  }
}

// ---- launcher -------------------------------------------------------------
extern "C" void kernel_launch(void* const* d_in, const int* in_sizes, int n_in,
                              void* d_out, int out_size, void* d_ws, size_t ws_size,
                              hipStream_t stream){
  const float* x   = (const float*)d_in[0];
  const float* Wf  = (const float*)d_in[1];
  const float* Rf  = (const float*)d_in[2];
  const float* bcf = (const float*)d_in[3];
  const float* Wb  = (const float*)d_in[4];
  const float* Rb  = (const float*)d_in[5];
  const float* bcb = (const float*)d_in[6];
  float* out = (float*)d_out;
  char* ws = (char*)d_ws;

  const size_t OFF_XH   = 0;                      // 16 MiB: x bf16
  const size_t OFF_WT   = 16777216;               // 1 MiB: W^T bf16 both dirs
  const size_t OFF_R4   = OFF_WT + 1048576;       // 1 MiB: R f16 packed
  const size_t OFF_STH  = OFF_R4 + 1048576;       // 32 KiB h state
  const size_t OFF_STC  = OFF_STH + 32768;        // 32 KiB c state
  const size_t OFF_PROJ = OFF_STC + 32768;        // proj chunk buffer

  unsigned short* xh   = (unsigned short*)(ws + OFF_XH);
  unsigned short* wt   = (unsigned short*)(ws + OFF_WT);
  uint4*          r4   = (uint4*)(ws + OFF_R4);
  float*          stH  = (float*)(ws + OFF_STH);
  float*          stC  = (float*)(ws + OFF_STC);
  unsigned short* proj = (unsigned short*)(ws + OFF_PROJ);

  int Tc = TT;  // time-chunk; shrink if ws too small (proj = 65536*Tc bytes)
  while (Tc > 128 && OFF_PROJ + (size_t)65536*Tc > ws_size) Tc >>= 1;

  cvt_x_kernel<<<8192, 256, 0, stream>>>(x, xh);
  cvt_wt_kernel<<<2048, 256, 0, stream>>>(Wf, Wb, wt);
  cvt_r_kernel<<<256, 256, 0, stream>>>(Rf, Rb, r4);

  int nch = TT / Tc;
  for (int ch = 0; ch < nch; ++ch){
    int t0 = ch*Tc, t1 = t0 + Tc;
    int grid = 8*(Tc >> 7)*16;
    gemm_proj<<<grid, 256, 0, stream>>>(xh, wt,          proj,                        t0,      Tc);
    gemm_proj<<<grid, 256, 0, stream>>>(xh, wt + 262144, proj + (size_t)16*Tc*GG,     TT - t1, Tc);
    lstm_scan<<<32, 512, 0, stream>>>(proj, r4, bcf, bcb, out, stH, stC, t0, t1, Tc, ch == 0 ? 1 : 0);
  }
}